// Round 1
// baseline (412.183 us; speedup 1.0000x reference)
//
#include <hip/hip_runtime.h>
#include <stddef.h>

#define DIM 1024
#define NH 16
#define HD 64
#define BATCH 2
#define SEQ 2048
#define ROWS (BATCH * SEQ) /* 4096 */

typedef short bf16x8 __attribute__((ext_vector_type(8)));
typedef float f32x4 __attribute__((ext_vector_type(4)));
typedef unsigned short u16;
typedef unsigned short u16x4v __attribute__((ext_vector_type(4)));

__device__ __forceinline__ u16 f2bf(float f) {
  union { float f; unsigned u; } v; v.f = f;
  unsigned r = v.u + 0x7FFFu + ((v.u >> 16) & 1u);
  return (u16)(r >> 16);
}

// ---------------- convert x (fp32 -> bf16) ----------------
__global__ __launch_bounds__(256) void convert_x(const float* __restrict__ x,
                                                 u16* __restrict__ xb) {
  int i = (blockIdx.x * 256 + threadIdx.x) * 4;
  float4 v = *(const float4*)(x + i);
  u16x4v o;
  o.x = f2bf(v.x); o.y = f2bf(v.y); o.z = f2bf(v.z); o.w = f2bf(v.w);
  *(u16x4v*)(xb + i) = o;
}

// ------- transpose + convert weights: WT[n][k] = w[k][n] (bf16) -------
__global__ __launch_bounds__(256) void transpose_w(
    const float* __restrict__ wq, const float* __restrict__ wk,
    const float* __restrict__ wv, const float* __restrict__ wo,
    u16* __restrict__ wqkvT, u16* __restrict__ woT) {
  __shared__ float tile[32][33];
  int bid = blockIdx.x;
  int mat = bid >> 10;       // 0..3
  int tIdx = bid & 1023;
  int tr = tIdx >> 5, tc = tIdx & 31;  // tr: k-tile, tc: n-tile
  const float* src = mat == 0 ? wq : mat == 1 ? wk : mat == 2 ? wv : wo;
  int t = threadIdx.x;
#pragma unroll
  for (int i = 0; i < 4; ++i) {
    int idx = i * 256 + t;
    int r = idx >> 5, c = idx & 31;
    tile[r][c] = src[(tr * 32 + r) * DIM + tc * 32 + c];
  }
  __syncthreads();
  u16* dst = (mat < 3) ? (wqkvT + mat * DIM * DIM) : woT;
#pragma unroll
  for (int i = 0; i < 4; ++i) {
    int idx = i * 256 + t;
    int r = idx >> 5, c = idx & 31;  // r: local n, c: local k
    dst[(tc * 32 + r) * DIM + tr * 32 + c] = f2bf(tile[c][r]);
  }
}

// ---------------- bf16 GEMM, B^T input (m97 pattern, 128x128 tile) ----
// C[m][n] = sum_k A[m][k] * BT[n][k]; A:[M][K], BT:[N][K] bf16; C fp32.
__global__ __launch_bounds__(256) void gemm_bt(
    const u16* __restrict__ A, const u16* __restrict__ BT,
    float* __restrict__ C, int M, int N, int K) {
  __shared__ u16 As[128][40];
  __shared__ u16 Bs[128][40];
  int ntn = N >> 7;
  int tm = blockIdx.x / ntn, tn = blockIdx.x % ntn;
  int m0 = tm << 7, n0 = tn << 7;
  int t = threadIdx.x;
  int w = t >> 6, lane = t & 63;
  int l15 = lane & 15, l4 = lane >> 4;
  int wr = w >> 1, wc = w & 1;

  f32x4 acc[4][4];
#pragma unroll
  for (int i = 0; i < 4; ++i)
#pragma unroll
    for (int j = 0; j < 4; ++j) acc[i][j] = (f32x4){0.f, 0.f, 0.f, 0.f};

  int sr = t >> 2;         // 0..63
  int sc = (t & 3) << 3;   // 0,8,16,24

  for (int kt = 0; kt < K; kt += 32) {
    __syncthreads();
#pragma unroll
    for (int p = 0; p < 2; ++p) {
      int r = p * 64 + sr;
      *(int4*)(&As[r][sc]) = *(const int4*)(A + (m0 + r) * K + kt + sc);
      *(int4*)(&Bs[r][sc]) = *(const int4*)(BT + (n0 + r) * K + kt + sc);
    }
    __syncthreads();
    bf16x8 af[4], bfr[4];
#pragma unroll
    for (int i = 0; i < 4; ++i)
      af[i] = *(const bf16x8*)(&As[wr * 64 + i * 16 + l15][l4 * 8]);
#pragma unroll
    for (int j = 0; j < 4; ++j)
      bfr[j] = *(const bf16x8*)(&Bs[wc * 64 + j * 16 + l15][l4 * 8]);
#pragma unroll
    for (int i = 0; i < 4; ++i)
#pragma unroll
      for (int j = 0; j < 4; ++j)
        acc[i][j] = __builtin_amdgcn_mfma_f32_16x16x32_bf16(af[i], bfr[j],
                                                            acc[i][j], 0, 0, 0);
  }
#pragma unroll
  for (int i = 0; i < 4; ++i)
#pragma unroll
    for (int j = 0; j < 4; ++j) {
      int m = m0 + wr * 64 + i * 16 + l4 * 4;
      int n = n0 + wc * 64 + j * 16 + l15;
#pragma unroll
      for (int r = 0; r < 4; ++r) C[(size_t)(m + r) * N + n] = acc[i][j][r];
    }
}

// ---- LN + rotary for Q,K rows; emits bf16 Q,K in [b][h][s][d] ----
__global__ __launch_bounds__(256) void post_qk(
    const float* __restrict__ qkv, const float* __restrict__ fsin,
    const float* __restrict__ fcos, const float* __restrict__ qsc,
    const float* __restrict__ qbi, const float* __restrict__ ksc,
    const float* __restrict__ kbi, u16* __restrict__ Q, u16* __restrict__ Kk) {
  int row = blockIdx.x;  // b*SEQ + s
  int b = row >> 11, s = row & 2047;
  int t = threadIdx.x;
  const float* qrow = qkv + (size_t)row * 3072;
  const float* krow = qrow + DIM;
  float4 qv = *(const float4*)(qrow + t * 4);
  float4 kv = *(const float4*)(krow + t * 4);
  float qsum = qv.x + qv.y + qv.z + qv.w;
  float qss = qv.x * qv.x + qv.y * qv.y + qv.z * qv.z + qv.w * qv.w;
  float ksum = kv.x + kv.y + kv.z + kv.w;
  float kss = kv.x * kv.x + kv.y * kv.y + kv.z * kv.z + kv.w * kv.w;
#pragma unroll
  for (int off = 1; off < 64; off <<= 1) {
    qsum += __shfl_xor(qsum, off, 64);
    qss += __shfl_xor(qss, off, 64);
    ksum += __shfl_xor(ksum, off, 64);
    kss += __shfl_xor(kss, off, 64);
  }
  __shared__ float red[4][4];
  int w = t >> 6;
  if ((t & 63) == 0) {
    red[w][0] = qsum; red[w][1] = qss; red[w][2] = ksum; red[w][3] = kss;
  }
  __syncthreads();
  qsum = red[0][0] + red[1][0] + red[2][0] + red[3][0];
  qss = red[0][1] + red[1][1] + red[2][1] + red[3][1];
  ksum = red[0][2] + red[1][2] + red[2][2] + red[3][2];
  kss = red[0][3] + red[1][3] + red[2][3] + red[3][3];
  const float inv = 1.0f / 1024.0f;
  float muq = qsum * inv;
  float rq = rsqrtf(qss * inv - muq * muq + 1e-6f);
  float muk = ksum * inv;
  float rk = rsqrtf(kss * inv - muk * muk + 1e-6f);

  int e0 = t * 4;
  int h = e0 >> 6, d0 = e0 & 63;
  float q0 = (qv.x - muq) * rq * qsc[e0 + 0] + qbi[e0 + 0];
  float q1 = (qv.y - muq) * rq * qsc[e0 + 1] + qbi[e0 + 1];
  float q2 = (qv.z - muq) * rq * qsc[e0 + 2] + qbi[e0 + 2];
  float q3 = (qv.w - muq) * rq * qsc[e0 + 3] + qbi[e0 + 3];
  float k0 = (kv.x - muk) * rk * ksc[e0 + 0] + kbi[e0 + 0];
  float k1 = (kv.y - muk) * rk * ksc[e0 + 1] + kbi[e0 + 1];
  float k2 = (kv.z - muk) * rk * ksc[e0 + 2] + kbi[e0 + 2];
  float k3 = (kv.w - muk) * rk * ksc[e0 + 3] + kbi[e0 + 3];

  int p0 = d0 >> 1;  // pair index (even); pairs p0 and p0+1
  float c0 = fcos[s * 32 + p0], s0 = fsin[s * 32 + p0];
  float c1 = fcos[s * 32 + p0 + 1], s1 = fsin[s * 32 + p0 + 1];
  float oq0 = q0 * c0 - q1 * s0, oq1 = q0 * s0 + q1 * c0;
  float oq2 = q2 * c1 - q3 * s1, oq3 = q2 * s1 + q3 * c1;
  float ok0 = k0 * c0 - k1 * s0, ok1 = k0 * s0 + k1 * c0;
  float ok2 = k2 * c1 - k3 * s1, ok3 = k2 * s1 + k3 * c1;

  const float QSC = 0.125f * 1.44269504088896340736f;  // 1/sqrt(64) * log2(e)
  u16x4v qo, ko;
  qo.x = f2bf(oq0 * QSC); qo.y = f2bf(oq1 * QSC);
  qo.z = f2bf(oq2 * QSC); qo.w = f2bf(oq3 * QSC);
  ko.x = f2bf(ok0); ko.y = f2bf(ok1); ko.z = f2bf(ok2); ko.w = f2bf(ok3);
  size_t base = ((size_t)(b * NH + h) * SEQ + s) * HD + d0;
  *(u16x4v*)(Q + base) = qo;
  *(u16x4v*)(Kk + base) = ko;
}

// ---- V transpose: Vt[b][h][d][s] bf16 from qkv fp32 ----
__global__ __launch_bounds__(256) void post_v(const float* __restrict__ qkv,
                                              u16* __restrict__ Vt) {
  __shared__ u16 vt[64][65];
  int bid = blockIdx.x;
  int st = bid & 31, bh = bid >> 5;  // s-tile, (b*NH+h)
  int b = bh >> 4, h = bh & 15;
  int t = threadIdx.x;
#pragma unroll
  for (int i = 0; i < 16; ++i) {
    int idx = i * 256 + t;
    int ss = idx >> 6, d = idx & 63;
    float v = qkv[(size_t)(b * SEQ + st * 64 + ss) * 3072 + 2048 + h * 64 + d];
    vt[ss][d] = f2bf(v);
  }
  __syncthreads();
#pragma unroll
  for (int i = 0; i < 16; ++i) {
    int idx = i * 256 + t;
    int dd = idx >> 6, ss = idx & 63;
    Vt[((size_t)bh * 64 + dd) * SEQ + st * 64 + ss] = vt[ss][dd];
  }
}

// ---- flash attention: Q[b][h][s][d], K same, Vt[b][h][d][s] -> O[b][s][h*64+d]
__global__ __launch_bounds__(256) void attn_fwd(const u16* __restrict__ Q,
                                                const u16* __restrict__ K,
                                                const u16* __restrict__ Vt,
                                                u16* __restrict__ O) {
  __shared__ u16 P[4][16][40];
  int bid = blockIdx.x;
  int qb = bid & 31, bh = bid >> 5;
  int b = bh >> 4, h = bh & 15;
  int t = threadIdx.x;
  int w = t >> 6, lane = t & 63;
  int l15 = lane & 15, l4 = lane >> 4;
  int q0 = qb * 64 + w * 16;
  const u16* Qh = Q + (size_t)bh * SEQ * HD;
  const u16* Kh = K + (size_t)bh * SEQ * HD;
  const u16* Vh = Vt + (size_t)bh * HD * SEQ;

  bf16x8 qf[2];
#pragma unroll
  for (int kf = 0; kf < 2; ++kf)
    qf[kf] = *(const bf16x8*)(Qh + (q0 + l15) * HD + kf * 32 + l4 * 8);

  f32x4 oacc[4];
#pragma unroll
  for (int df = 0; df < 4; ++df) oacc[df] = (f32x4){0.f, 0.f, 0.f, 0.f};
  float mrow[4], lrow[4];
#pragma unroll
  for (int r = 0; r < 4; ++r) { mrow[r] = -1e30f; lrow[r] = 0.f; }

  for (int j0 = 0; j0 < SEQ; j0 += 32) {
    f32x4 sacc[2];
    sacc[0] = (f32x4){0.f, 0.f, 0.f, 0.f};
    sacc[1] = (f32x4){0.f, 0.f, 0.f, 0.f};
#pragma unroll
    for (int nf = 0; nf < 2; ++nf)
#pragma unroll
      for (int kf = 0; kf < 2; ++kf) {
        bf16x8 kfr =
            *(const bf16x8*)(Kh + (j0 + nf * 16 + l15) * HD + kf * 32 + l4 * 8);
        sacc[nf] =
            __builtin_amdgcn_mfma_f32_16x16x32_bf16(qf[kf], kfr, sacc[nf], 0, 0, 0);
      }
    // online softmax (log2 domain; Q pre-scaled by 0.125*log2e)
    float pmax[4];
#pragma unroll
    for (int r = 0; r < 4; ++r) pmax[r] = fmaxf(sacc[0][r], sacc[1][r]);
#pragma unroll
    for (int off = 1; off < 16; off <<= 1)
#pragma unroll
      for (int r = 0; r < 4; ++r)
        pmax[r] = fmaxf(pmax[r], __shfl_xor(pmax[r], off, 64));
    float scl[4];
#pragma unroll
    for (int r = 0; r < 4; ++r) {
      float mn = fmaxf(mrow[r], pmax[r]);
      scl[r] = exp2f(mrow[r] - mn);
      mrow[r] = mn;
    }
    float p[2][4];
#pragma unroll
    for (int nf = 0; nf < 2; ++nf)
#pragma unroll
      for (int r = 0; r < 4; ++r) p[nf][r] = exp2f(sacc[nf][r] - mrow[r]);
    float rs[4];
#pragma unroll
    for (int r = 0; r < 4; ++r) rs[r] = p[0][r] + p[1][r];
#pragma unroll
    for (int off = 1; off < 16; off <<= 1)
#pragma unroll
      for (int r = 0; r < 4; ++r) rs[r] += __shfl_xor(rs[r], off, 64);
#pragma unroll
    for (int r = 0; r < 4; ++r) lrow[r] = lrow[r] * scl[r] + rs[r];
#pragma unroll
    for (int df = 0; df < 4; ++df)
#pragma unroll
      for (int r = 0; r < 4; ++r) oacc[df][r] *= scl[r];
    // P transpose via per-wave LDS (in-wave, DS ops are in-order)
#pragma unroll
    for (int nf = 0; nf < 2; ++nf)
#pragma unroll
      for (int r = 0; r < 4; ++r)
        P[w][l4 * 4 + r][nf * 16 + l15] = f2bf(p[nf][r]);
    asm volatile("s_waitcnt lgkmcnt(0)" ::: "memory");
    __builtin_amdgcn_sched_barrier(0);
    bf16x8 pf = *(const bf16x8*)(&P[w][l15][l4 * 8]);
#pragma unroll
    for (int df = 0; df < 4; ++df) {
      bf16x8 vf = *(const bf16x8*)(Vh + (df * 16 + l15) * SEQ + j0 + l4 * 8);
      oacc[df] = __builtin_amdgcn_mfma_f32_16x16x32_bf16(pf, vf, oacc[df], 0, 0, 0);
    }
  }
#pragma unroll
  for (int df = 0; df < 4; ++df) {
    int dcol = h * 64 + df * 16 + l15;
#pragma unroll
    for (int r = 0; r < 4; ++r) {
      float v = oacc[df][r] / lrow[r];
      O[(size_t)(b * SEQ + q0 + l4 * 4 + r) * DIM + dcol] = f2bf(v);
    }
  }
}

extern "C" void kernel_launch(void* const* d_in, const int* in_sizes, int n_in,
                              void* d_out, int out_size, void* d_ws,
                              size_t ws_size, hipStream_t stream) {
  const float* x = (const float*)d_in[0];
  const float* fsin = (const float*)d_in[1];
  const float* fcos = (const float*)d_in[2];
  const float* wq = (const float*)d_in[3];
  const float* wk = (const float*)d_in[4];
  const float* wv = (const float*)d_in[5];
  const float* wo = (const float*)d_in[6];
  const float* q_scale = (const float*)d_in[7];
  const float* q_bias = (const float*)d_in[8];
  const float* k_scale = (const float*)d_in[9];
  const float* k_bias = (const float*)d_in[10];
  float* out = (float*)d_out;

  u16* xb = (u16*)d_ws;                       // 4096*1024 bf16
  u16* wqkvT = xb + (size_t)ROWS * DIM;       // 3072*1024
  u16* woT = wqkvT + (size_t)3 * DIM * DIM;   // 1024*1024
  float* qkv = (float*)(woT + (size_t)DIM * DIM);  // 4096*3072 fp32
  u16* Qb = (u16*)(qkv + (size_t)ROWS * 3 * DIM);  // 32*2048*64
  u16* Kb = Qb + (size_t)BATCH * NH * SEQ * HD;
  u16* Vt = Kb + (size_t)BATCH * NH * SEQ * HD;
  u16* attnb = Vt + (size_t)BATCH * NH * SEQ * HD;  // 4096*1024

  convert_x<<<ROWS * DIM / 1024, 256, 0, stream>>>(x, xb);
  transpose_w<<<4 * 1024, 256, 0, stream>>>(wq, wk, wv, wo, wqkvT, woT);
  gemm_bt<<<(ROWS / 128) * (3 * DIM / 128), 256, 0, stream>>>(xb, wqkvT, qkv,
                                                              ROWS, 3 * DIM, DIM);
  post_qk<<<ROWS, 256, 0, stream>>>(qkv, fsin, fcos, q_scale, q_bias, k_scale,
                                    k_bias, Qb, Kb);
  post_v<<<BATCH * NH * (SEQ / 64), 256, 0, stream>>>(qkv, Vt);
  attn_fwd<<<BATCH * NH * (SEQ / 64), 256, 0, stream>>>(Qb, Kb, Vt, attnb);
  gemm_bt<<<(ROWS / 128) * (DIM / 128), 256, 0, stream>>>(attnb, woT, out, ROWS,
                                                          DIM, DIM);
}

// Round 2
// 404.254 us; speedup vs baseline: 1.0196x; 1.0196x over previous
//
#include <hip/hip_runtime.h>
#include <stddef.h>
#include <stdint.h>

#define DIM 1024
#define NH 16
#define HD 64
#define BATCH 2
#define SEQ 2048
#define ROWS (BATCH * SEQ) /* 4096 */

typedef short bf16x8 __attribute__((ext_vector_type(8)));
typedef float f32x4 __attribute__((ext_vector_type(4)));
typedef unsigned short u16;
typedef unsigned short u16x4v __attribute__((ext_vector_type(4)));

#define AS1 __attribute__((address_space(1)))
#define AS3 __attribute__((address_space(3)))

__device__ __forceinline__ void gload16(const u16* g, u16* l) {
  __builtin_amdgcn_global_load_lds((const AS1 void*)g, (AS3 void*)l, 16, 0, 0);
}

__device__ __forceinline__ u16 f2bf(float f) {
  union { float f; unsigned u; } v; v.f = f;
  unsigned r = v.u + 0x7FFFu + ((v.u >> 16) & 1u);
  return (u16)(r >> 16);
}

// ---------------- convert x (fp32 -> bf16) ----------------
__global__ __launch_bounds__(256) void convert_x(const float* __restrict__ x,
                                                 u16* __restrict__ xb) {
  int i = (blockIdx.x * 256 + threadIdx.x) * 4;
  float4 v = *(const float4*)(x + i);
  u16x4v o;
  o.x = f2bf(v.x); o.y = f2bf(v.y); o.z = f2bf(v.z); o.w = f2bf(v.w);
  *(u16x4v*)(xb + i) = o;
}

// ------- transpose + convert weights: WT[n][k] = w[k][n] (bf16) -------
__global__ __launch_bounds__(256) void transpose_w(
    const float* __restrict__ wq, const float* __restrict__ wk,
    const float* __restrict__ wv, const float* __restrict__ wo,
    u16* __restrict__ wqkvT, u16* __restrict__ woT) {
  __shared__ float tile[32][33];
  int bid = blockIdx.x;
  int mat = bid >> 10;       // 0..3
  int tIdx = bid & 1023;
  int tr = tIdx >> 5, tc = tIdx & 31;  // tr: k-tile, tc: n-tile
  const float* src = mat == 0 ? wq : mat == 1 ? wk : mat == 2 ? wv : wo;
  int t = threadIdx.x;
#pragma unroll
  for (int i = 0; i < 4; ++i) {
    int idx = i * 256 + t;
    int r = idx >> 5, c = idx & 31;
    tile[r][c] = src[(tr * 32 + r) * DIM + tc * 32 + c];
  }
  __syncthreads();
  u16* dst = (mat < 3) ? (wqkvT + mat * DIM * DIM) : woT;
#pragma unroll
  for (int i = 0; i < 4; ++i) {
    int idx = i * 256 + t;
    int r = idx >> 5, c = idx & 31;  // r: local n, c: local k
    dst[(tc * 32 + r) * DIM + tr * 32 + c] = f2bf(tile[c][r]);
  }
}

// ------- bf16 GEMM, B^T input (m97 structure: 128x128 tile, BK=32,
//         global_load_lds width-16, linear LDS) -------
// C[m][n] = sum_k A[m][k] * BT[n][k]; A:[M][K], BT:[N][K] bf16; C fp32.
__global__ __launch_bounds__(256) void gemm_bt(
    const u16* __restrict__ A, const u16* __restrict__ BT,
    float* __restrict__ C, int M, int N, int K) {
  __shared__ u16 As[128 * 32];
  __shared__ u16 Bs[128 * 32];
  int ntn = N >> 7;
  int tm = blockIdx.x / ntn, tn = blockIdx.x % ntn;
  int m0 = tm << 7, n0 = tn << 7;
  int t = threadIdx.x;
  int w = t >> 6, lane = t & 63;
  int l15 = lane & 15, l4 = lane >> 4;
  int wr = w >> 1, wc = w & 1;

  f32x4 acc[4][4];
#pragma unroll
  for (int i = 0; i < 4; ++i)
#pragma unroll
    for (int j = 0; j < 4; ++j) acc[i][j] = (f32x4){0.f, 0.f, 0.f, 0.f};

  // staging: LDS u16 offset = t*8 (+2048 for second half); row = t/4, col = (t&3)*8
  int srow = t >> 2, scol = (t & 3) << 3;
  const u16* Ag = A + (size_t)(m0 + srow) * K + scol;
  const u16* Bg = BT + (size_t)(n0 + srow) * K + scol;
  u16* Asl = &As[t * 8];
  u16* Bsl = &Bs[t * 8];
  size_t half = (size_t)64 * K;

  for (int kt = 0; kt < K; kt += 32) {
    __syncthreads();
    gload16(Ag + kt, Asl);
    gload16(Ag + half + kt, Asl + 2048);
    gload16(Bg + kt, Bsl);
    gload16(Bg + half + kt, Bsl + 2048);
    __syncthreads();
    bf16x8 af[4], bfr[4];
#pragma unroll
    for (int i = 0; i < 4; ++i)
      af[i] = *(const bf16x8*)(&As[(wr * 64 + i * 16 + l15) * 32 + l4 * 8]);
#pragma unroll
    for (int j = 0; j < 4; ++j)
      bfr[j] = *(const bf16x8*)(&Bs[(wc * 64 + j * 16 + l15) * 32 + l4 * 8]);
#pragma unroll
    for (int i = 0; i < 4; ++i)
#pragma unroll
      for (int j = 0; j < 4; ++j)
        acc[i][j] = __builtin_amdgcn_mfma_f32_16x16x32_bf16(af[i], bfr[j],
                                                            acc[i][j], 0, 0, 0);
  }
#pragma unroll
  for (int i = 0; i < 4; ++i)
#pragma unroll
    for (int j = 0; j < 4; ++j) {
      int m = m0 + wr * 64 + i * 16 + l4 * 4;
      int n = n0 + wc * 64 + j * 16 + l15;
#pragma unroll
      for (int r = 0; r < 4; ++r) C[(size_t)(m + r) * N + n] = acc[i][j][r];
    }
}

// ---- LN + rotary for Q,K rows; emits bf16 Q,K in [b][h][s][d] ----
__global__ __launch_bounds__(256) void post_qk(
    const float* __restrict__ qkv, const float* __restrict__ fsin,
    const float* __restrict__ fcos, const float* __restrict__ qsc,
    const float* __restrict__ qbi, const float* __restrict__ ksc,
    const float* __restrict__ kbi, u16* __restrict__ Q, u16* __restrict__ Kk) {
  int row = blockIdx.x;  // b*SEQ + s
  int b = row >> 11, s = row & 2047;
  int t = threadIdx.x;
  const float* qrow = qkv + (size_t)row * 3072;
  const float* krow = qrow + DIM;
  float4 qv = *(const float4*)(qrow + t * 4);
  float4 kv = *(const float4*)(krow + t * 4);
  float qsum = qv.x + qv.y + qv.z + qv.w;
  float qss = qv.x * qv.x + qv.y * qv.y + qv.z * qv.z + qv.w * qv.w;
  float ksum = kv.x + kv.y + kv.z + kv.w;
  float kss = kv.x * kv.x + kv.y * kv.y + kv.z * kv.z + kv.w * kv.w;
#pragma unroll
  for (int off = 1; off < 64; off <<= 1) {
    qsum += __shfl_xor(qsum, off, 64);
    qss += __shfl_xor(qss, off, 64);
    ksum += __shfl_xor(ksum, off, 64);
    kss += __shfl_xor(kss, off, 64);
  }
  __shared__ float red[4][4];
  int w = t >> 6;
  if ((t & 63) == 0) {
    red[w][0] = qsum; red[w][1] = qss; red[w][2] = ksum; red[w][3] = kss;
  }
  __syncthreads();
  qsum = red[0][0] + red[1][0] + red[2][0] + red[3][0];
  qss = red[0][1] + red[1][1] + red[2][1] + red[3][1];
  ksum = red[0][2] + red[1][2] + red[2][2] + red[3][2];
  kss = red[0][3] + red[1][3] + red[2][3] + red[3][3];
  const float inv = 1.0f / 1024.0f;
  float muq = qsum * inv;
  float rq = rsqrtf(qss * inv - muq * muq + 1e-6f);
  float muk = ksum * inv;
  float rk = rsqrtf(kss * inv - muk * muk + 1e-6f);

  int e0 = t * 4;
  int h = e0 >> 6, d0 = e0 & 63;
  float q0 = (qv.x - muq) * rq * qsc[e0 + 0] + qbi[e0 + 0];
  float q1 = (qv.y - muq) * rq * qsc[e0 + 1] + qbi[e0 + 1];
  float q2 = (qv.z - muq) * rq * qsc[e0 + 2] + qbi[e0 + 2];
  float q3 = (qv.w - muq) * rq * qsc[e0 + 3] + qbi[e0 + 3];
  float k0 = (kv.x - muk) * rk * ksc[e0 + 0] + kbi[e0 + 0];
  float k1 = (kv.y - muk) * rk * ksc[e0 + 1] + kbi[e0 + 1];
  float k2 = (kv.z - muk) * rk * ksc[e0 + 2] + kbi[e0 + 2];
  float k3 = (kv.w - muk) * rk * ksc[e0 + 3] + kbi[e0 + 3];

  int p0 = d0 >> 1;  // pair index (even); pairs p0 and p0+1
  float c0 = fcos[s * 32 + p0], s0 = fsin[s * 32 + p0];
  float c1 = fcos[s * 32 + p0 + 1], s1 = fsin[s * 32 + p0 + 1];
  float oq0 = q0 * c0 - q1 * s0, oq1 = q0 * s0 + q1 * c0;
  float oq2 = q2 * c1 - q3 * s1, oq3 = q2 * s1 + q3 * c1;
  float ok0 = k0 * c0 - k1 * s0, ok1 = k0 * s0 + k1 * c0;
  float ok2 = k2 * c1 - k3 * s1, ok3 = k2 * s1 + k3 * c1;

  const float QSC = 0.125f * 1.44269504088896340736f;  // 1/sqrt(64) * log2(e)
  u16x4v qo, ko;
  qo.x = f2bf(oq0 * QSC); qo.y = f2bf(oq1 * QSC);
  qo.z = f2bf(oq2 * QSC); qo.w = f2bf(oq3 * QSC);
  ko.x = f2bf(ok0); ko.y = f2bf(ok1); ko.z = f2bf(ok2); ko.w = f2bf(ok3);
  size_t base = ((size_t)(b * NH + h) * SEQ + s) * HD + d0;
  *(u16x4v*)(Q + base) = qo;
  *(u16x4v*)(Kk + base) = ko;
}

// ---- V transpose: Vt[b][h][d][s] bf16 from qkv fp32 ----
__global__ __launch_bounds__(256) void post_v(const float* __restrict__ qkv,
                                              u16* __restrict__ Vt) {
  __shared__ u16 vt[64][65];
  int bid = blockIdx.x;
  int st = bid & 31, bh = bid >> 5;  // s-tile, (b*NH+h)
  int b = bh >> 4, h = bh & 15;
  int t = threadIdx.x;
#pragma unroll
  for (int i = 0; i < 16; ++i) {
    int idx = i * 256 + t;
    int ss = idx >> 6, d = idx & 63;
    float v = qkv[(size_t)(b * SEQ + st * 64 + ss) * 3072 + 2048 + h * 64 + d];
    vt[ss][d] = f2bf(v);
  }
  __syncthreads();
#pragma unroll
  for (int i = 0; i < 16; ++i) {
    int idx = i * 256 + t;
    int dd = idx >> 6, ss = idx & 63;
    Vt[((size_t)bh * 64 + dd) * SEQ + st * 64 + ss] = vt[ss][dd];
  }
}

// ---- flash attention, swapped-QK^T in-register softmax ----
// Q[b][h][s][d], K same, Vt[b][h][d][s] -> O[b][s][h*64+d] (bf16)
// Per wave: 16 q-rows, KVBLK=64. Lane (q=l15, g=l4) holds S[q][nf*16+g*4+r].
__global__ __launch_bounds__(256, 4) void attn_fwd(const u16* __restrict__ Q,
                                                   const u16* __restrict__ K,
                                                   const u16* __restrict__ Vt,
                                                   u16* __restrict__ O) {
  __shared__ u16 P[4][16][80];  // per-wave P^T staging, padded (even bank spread)
  int bid = blockIdx.x;
  int qb = bid & 31, bh = bid >> 5;
  int b = bh >> 4, h = bh & 15;
  int t = threadIdx.x;
  int w = t >> 6, lane = t & 63;
  int l15 = lane & 15, l4 = lane >> 4;
  int q0 = qb * 64 + w * 16;
  const u16* Qh = Q + (size_t)bh * SEQ * HD;
  const u16* Kh = K + (size_t)bh * SEQ * HD;
  const u16* Vh = Vt + (size_t)bh * HD * SEQ;

  bf16x8 qf[2];
#pragma unroll
  for (int kf = 0; kf < 2; ++kf)
    qf[kf] = *(const bf16x8*)(Qh + (size_t)(q0 + l15) * HD + kf * 32 + l4 * 8);

  f32x4 oacc[4];
#pragma unroll
  for (int df = 0; df < 4; ++df) oacc[df] = (f32x4){0.f, 0.f, 0.f, 0.f};
  float mrun = -1e30f, lpart = 0.f;

  for (int j0 = 0; j0 < SEQ; j0 += 64) {
    // QK^T swapped: A=K rows, B=Q rows -> S^T
    f32x4 sacc[4];
#pragma unroll
    for (int nf = 0; nf < 4; ++nf) sacc[nf] = (f32x4){0.f, 0.f, 0.f, 0.f};
#pragma unroll
    for (int nf = 0; nf < 4; ++nf)
#pragma unroll
      for (int kf = 0; kf < 2; ++kf) {
        bf16x8 kfr = *(const bf16x8*)(Kh + (size_t)(j0 + nf * 16 + l15) * HD +
                                      kf * 32 + l4 * 8);
        sacc[nf] =
            __builtin_amdgcn_mfma_f32_16x16x32_bf16(kfr, qf[kf], sacc[nf], 0, 0, 0);
      }
    // prefetch V fragments (independent of softmax chain)
    bf16x8 vf[2][4];
#pragma unroll
    for (int kc = 0; kc < 2; ++kc)
#pragma unroll
      for (int df = 0; df < 4; ++df)
        vf[kc][df] = *(const bf16x8*)(Vh + (size_t)(df * 16 + l15) * SEQ + j0 +
                                      kc * 32 + l4 * 8);
    // per-lane max over its 16 keys, then 2-shuffle cross-g reduce
    float m16 = sacc[0][0];
#pragma unroll
    for (int nf = 0; nf < 4; ++nf)
#pragma unroll
      for (int r = 0; r < 4; ++r) m16 = fmaxf(m16, sacc[nf][r]);
    m16 = fmaxf(m16, __shfl_xor(m16, 16, 64));
    m16 = fmaxf(m16, __shfl_xor(m16, 32, 64));
    // defer-max (T13): only rescale when max grew by > 8 (log2 domain)
    if (!__all(m16 - mrun <= 8.0f)) {
      float mnew = fmaxf(mrun, m16);
      float scl = exp2f(mrun - mnew);
      mrun = mnew;
      lpart *= scl;
      float sr[4];
#pragma unroll
      for (int r = 0; r < 4; ++r) sr[r] = __shfl(scl, l4 * 4 + r, 16);
#pragma unroll
      for (int df = 0; df < 4; ++df)
#pragma unroll
        for (int r = 0; r < 4; ++r) oacc[df][r] *= sr[r];
    }
    // p = exp2(s - m); per-lane partial rowsum (cross-lane reduce deferred)
    float rs = 0.f;
#pragma unroll
    for (int nf = 0; nf < 4; ++nf) {
      u16x4v pk;
#pragma unroll
      for (int r = 0; r < 4; ++r) {
        float pv = exp2f(sacc[nf][r] - mrun);
        rs += pv;
        pk[r] = f2bf(pv);
      }
      *(u16x4v*)(&P[w][l15][nf * 16 + l4 * 4]) = pk;
    }
    lpart += rs;
    asm volatile("s_waitcnt lgkmcnt(0)" ::: "memory");
    __builtin_amdgcn_sched_barrier(0);
#pragma unroll
    for (int kc = 0; kc < 2; ++kc) {
      bf16x8 pf = *(const bf16x8*)(&P[w][l15][kc * 32 + l4 * 8]);
#pragma unroll
      for (int df = 0; df < 4; ++df)
        oacc[df] =
            __builtin_amdgcn_mfma_f32_16x16x32_bf16(pf, vf[kc][df], oacc[df], 0, 0, 0);
    }
  }
  // deferred l reduction + epilogue
  lpart += __shfl_xor(lpart, 16, 64);
  lpart += __shfl_xor(lpart, 32, 64);
  float lr[4];
#pragma unroll
  for (int r = 0; r < 4; ++r) lr[r] = 1.0f / __shfl(lpart, l4 * 4 + r, 16);
#pragma unroll
  for (int df = 0; df < 4; ++df) {
    int dcol = h * 64 + df * 16 + l15;
#pragma unroll
    for (int r = 0; r < 4; ++r)
      O[(size_t)(b * SEQ + q0 + l4 * 4 + r) * DIM + dcol] = f2bf(oacc[df][r] * lr[r]);
  }
}

extern "C" void kernel_launch(void* const* d_in, const int* in_sizes, int n_in,
                              void* d_out, int out_size, void* d_ws,
                              size_t ws_size, hipStream_t stream) {
  const float* x = (const float*)d_in[0];
  const float* fsin = (const float*)d_in[1];
  const float* fcos = (const float*)d_in[2];
  const float* wq = (const float*)d_in[3];
  const float* wk = (const float*)d_in[4];
  const float* wv = (const float*)d_in[5];
  const float* wo = (const float*)d_in[6];
  const float* q_scale = (const float*)d_in[7];
  const float* q_bias = (const float*)d_in[8];
  const float* k_scale = (const float*)d_in[9];
  const float* k_bias = (const float*)d_in[10];
  float* out = (float*)d_out;

  u16* xb = (u16*)d_ws;                       // 4096*1024 bf16
  u16* wqkvT = xb + (size_t)ROWS * DIM;       // 3072*1024
  u16* woT = wqkvT + (size_t)3 * DIM * DIM;   // 1024*1024
  float* qkv = (float*)(woT + (size_t)DIM * DIM);  // 4096*3072 fp32
  u16* Qb = (u16*)(qkv + (size_t)ROWS * 3 * DIM);  // 32*2048*64
  u16* Kb = Qb + (size_t)BATCH * NH * SEQ * HD;
  u16* Vt = Kb + (size_t)BATCH * NH * SEQ * HD;
  u16* attnb = Vt + (size_t)BATCH * NH * SEQ * HD;  // 4096*1024

  convert_x<<<ROWS * DIM / 1024, 256, 0, stream>>>(x, xb);
  transpose_w<<<4 * 1024, 256, 0, stream>>>(wq, wk, wv, wo, wqkvT, woT);
  gemm_bt<<<(ROWS / 128) * (3 * DIM / 128), 256, 0, stream>>>(xb, wqkvT, qkv,
                                                              ROWS, 3 * DIM, DIM);
  post_qk<<<ROWS, 256, 0, stream>>>(qkv, fsin, fcos, q_scale, q_bias, k_scale,
                                    k_bias, Qb, Kb);
  post_v<<<BATCH * NH * (SEQ / 64), 256, 0, stream>>>(qkv, Vt);
  attn_fwd<<<BATCH * NH * (SEQ / 64), 256, 0, stream>>>(Qb, Kb, Vt, attnb);
  gemm_bt<<<(ROWS / 128) * (DIM / 128), 256, 0, stream>>>(attnb, woT, out, ROWS,
                                                          DIM, DIM);
}

// Round 3
// 274.892 us; speedup vs baseline: 1.4994x; 1.4706x over previous
//
#include <hip/hip_runtime.h>
#include <stddef.h>
#include <stdint.h>

#define DIM 1024
#define NH 16
#define HD 64
#define BATCH 2
#define SEQ 2048
#define ROWS (BATCH * SEQ) /* 4096 */
#define KVB 64
#define NT (SEQ / KVB)

typedef short bf16x8 __attribute__((ext_vector_type(8)));
typedef float f32x4 __attribute__((ext_vector_type(4)));
typedef unsigned short u16;
typedef unsigned short u16x4v __attribute__((ext_vector_type(4)));

#define AS1 __attribute__((address_space(1)))
#define AS3 __attribute__((address_space(3)))

__device__ __forceinline__ void gload16(const u16* g, u16* l) {
  __builtin_amdgcn_global_load_lds((const AS1 void*)g, (AS3 void*)l, 16, 0, 0);
}

__device__ __forceinline__ u16 f2bf(float f) {
  union { float f; unsigned u; } v; v.f = f;
  unsigned r = v.u + 0x7FFFu + ((v.u >> 16) & 1u);
  return (u16)(r >> 16);
}

// ---------------- convert x (fp32 -> bf16) ----------------
__global__ __launch_bounds__(256) void convert_x(const float* __restrict__ x,
                                                 u16* __restrict__ xb) {
  int i = (blockIdx.x * 256 + threadIdx.x) * 4;
  float4 v = *(const float4*)(x + i);
  u16x4v o;
  o.x = f2bf(v.x); o.y = f2bf(v.y); o.z = f2bf(v.z); o.w = f2bf(v.w);
  *(u16x4v*)(xb + i) = o;
}

// ------- transpose + convert weights: WT[n][k] = w[k][n] (bf16) -------
__global__ __launch_bounds__(256) void transpose_w(
    const float* __restrict__ wq, const float* __restrict__ wk,
    const float* __restrict__ wv, const float* __restrict__ wo,
    u16* __restrict__ wqkvT, u16* __restrict__ woT) {
  __shared__ float tile[32][33];
  int bid = blockIdx.x;
  int mat = bid >> 10;       // 0..3
  int tIdx = bid & 1023;
  int tr = tIdx >> 5, tc = tIdx & 31;  // tr: k-tile, tc: n-tile
  const float* src = mat == 0 ? wq : mat == 1 ? wk : mat == 2 ? wv : wo;
  int t = threadIdx.x;
#pragma unroll
  for (int i = 0; i < 4; ++i) {
    int idx = i * 256 + t;
    int r = idx >> 5, c = idx & 31;
    tile[r][c] = src[(tr * 32 + r) * DIM + tc * 32 + c];
  }
  __syncthreads();
  u16* dst = (mat < 3) ? (wqkvT + mat * DIM * DIM) : woT;
#pragma unroll
  for (int i = 0; i < 4; ++i) {
    int idx = i * 256 + t;
    int r = idx >> 5, c = idx & 31;  // r: local n, c: local k
    dst[(tc * 32 + r) * DIM + tr * 32 + c] = f2bf(tile[c][r]);
  }
}

// ------- bf16 GEMM, B^T input (m97 structure: 128x128 tile, BK=32,
//         global_load_lds width-16, linear LDS) -------
// C[m][n] = sum_k A[m][k] * BT[n][k]; A:[M][K], BT:[N][K] bf16; C fp32.
__global__ __launch_bounds__(256) void gemm_bt(
    const u16* __restrict__ A, const u16* __restrict__ BT,
    float* __restrict__ C, int M, int N, int K) {
  __shared__ u16 As[128 * 32];
  __shared__ u16 Bs[128 * 32];
  int ntn = N >> 7;
  int tm = blockIdx.x / ntn, tn = blockIdx.x % ntn;
  int m0 = tm << 7, n0 = tn << 7;
  int t = threadIdx.x;
  int w = t >> 6, lane = t & 63;
  int l15 = lane & 15, l4 = lane >> 4;
  int wr = w >> 1, wc = w & 1;

  f32x4 acc[4][4];
#pragma unroll
  for (int i = 0; i < 4; ++i)
#pragma unroll
    for (int j = 0; j < 4; ++j) acc[i][j] = (f32x4){0.f, 0.f, 0.f, 0.f};

  int srow = t >> 2, scol = (t & 3) << 3;
  const u16* Ag = A + (size_t)(m0 + srow) * K + scol;
  const u16* Bg = BT + (size_t)(n0 + srow) * K + scol;
  u16* Asl = &As[t * 8];
  u16* Bsl = &Bs[t * 8];
  size_t half = (size_t)64 * K;

  for (int kt = 0; kt < K; kt += 32) {
    __syncthreads();
    gload16(Ag + kt, Asl);
    gload16(Ag + half + kt, Asl + 2048);
    gload16(Bg + kt, Bsl);
    gload16(Bg + half + kt, Bsl + 2048);
    __syncthreads();
    bf16x8 af[4], bfr[4];
#pragma unroll
    for (int i = 0; i < 4; ++i)
      af[i] = *(const bf16x8*)(&As[(wr * 64 + i * 16 + l15) * 32 + l4 * 8]);
#pragma unroll
    for (int j = 0; j < 4; ++j)
      bfr[j] = *(const bf16x8*)(&Bs[(wc * 64 + j * 16 + l15) * 32 + l4 * 8]);
#pragma unroll
    for (int i = 0; i < 4; ++i)
#pragma unroll
      for (int j = 0; j < 4; ++j)
        acc[i][j] = __builtin_amdgcn_mfma_f32_16x16x32_bf16(af[i], bfr[j],
                                                            acc[i][j], 0, 0, 0);
  }
#pragma unroll
  for (int i = 0; i < 4; ++i)
#pragma unroll
    for (int j = 0; j < 4; ++j) {
      int m = m0 + wr * 64 + i * 16 + l4 * 4;
      int n = n0 + wc * 64 + j * 16 + l15;
#pragma unroll
      for (int r = 0; r < 4; ++r) C[(size_t)(m + r) * N + n] = acc[i][j][r];
    }
}

// ---- LN + rotary for Q,K rows; emits bf16 Q,K in [b][h][s][d] ----
__global__ __launch_bounds__(256) void post_qk(
    const float* __restrict__ qkv, const float* __restrict__ fsin,
    const float* __restrict__ fcos, const float* __restrict__ qsc,
    const float* __restrict__ qbi, const float* __restrict__ ksc,
    const float* __restrict__ kbi, u16* __restrict__ Q, u16* __restrict__ Kk) {
  int row = blockIdx.x;  // b*SEQ + s
  int b = row >> 11, s = row & 2047;
  int t = threadIdx.x;
  const float* qrow = qkv + (size_t)row * 3072;
  const float* krow = qrow + DIM;
  float4 qv = *(const float4*)(qrow + t * 4);
  float4 kv = *(const float4*)(krow + t * 4);
  float qsum = qv.x + qv.y + qv.z + qv.w;
  float qss = qv.x * qv.x + qv.y * qv.y + qv.z * qv.z + qv.w * qv.w;
  float ksum = kv.x + kv.y + kv.z + kv.w;
  float kss = kv.x * kv.x + kv.y * kv.y + kv.z * kv.z + kv.w * kv.w;
#pragma unroll
  for (int off = 1; off < 64; off <<= 1) {
    qsum += __shfl_xor(qsum, off, 64);
    qss += __shfl_xor(qss, off, 64);
    ksum += __shfl_xor(ksum, off, 64);
    kss += __shfl_xor(kss, off, 64);
  }
  __shared__ float red[4][4];
  int w = t >> 6;
  if ((t & 63) == 0) {
    red[w][0] = qsum; red[w][1] = qss; red[w][2] = ksum; red[w][3] = kss;
  }
  __syncthreads();
  qsum = red[0][0] + red[1][0] + red[2][0] + red[3][0];
  qss = red[0][1] + red[1][1] + red[2][1] + red[3][1];
  ksum = red[0][2] + red[1][2] + red[2][2] + red[3][2];
  kss = red[0][3] + red[1][3] + red[2][3] + red[3][3];
  const float inv = 1.0f / 1024.0f;
  float muq = qsum * inv;
  float rq = rsqrtf(qss * inv - muq * muq + 1e-6f);
  float muk = ksum * inv;
  float rk = rsqrtf(kss * inv - muk * muk + 1e-6f);

  int e0 = t * 4;
  int h = e0 >> 6, d0 = e0 & 63;
  float q0 = (qv.x - muq) * rq * qsc[e0 + 0] + qbi[e0 + 0];
  float q1 = (qv.y - muq) * rq * qsc[e0 + 1] + qbi[e0 + 1];
  float q2 = (qv.z - muq) * rq * qsc[e0 + 2] + qbi[e0 + 2];
  float q3 = (qv.w - muq) * rq * qsc[e0 + 3] + qbi[e0 + 3];
  float k0 = (kv.x - muk) * rk * ksc[e0 + 0] + kbi[e0 + 0];
  float k1 = (kv.y - muk) * rk * ksc[e0 + 1] + kbi[e0 + 1];
  float k2 = (kv.z - muk) * rk * ksc[e0 + 2] + kbi[e0 + 2];
  float k3 = (kv.w - muk) * rk * ksc[e0 + 3] + kbi[e0 + 3];

  int p0 = d0 >> 1;
  float c0 = fcos[s * 32 + p0], s0 = fsin[s * 32 + p0];
  float c1 = fcos[s * 32 + p0 + 1], s1 = fsin[s * 32 + p0 + 1];
  float oq0 = q0 * c0 - q1 * s0, oq1 = q0 * s0 + q1 * c0;
  float oq2 = q2 * c1 - q3 * s1, oq3 = q2 * s1 + q3 * c1;
  float ok0 = k0 * c0 - k1 * s0, ok1 = k0 * s0 + k1 * c0;
  float ok2 = k2 * c1 - k3 * s1, ok3 = k2 * s1 + k3 * c1;

  const float QSC = 0.125f * 1.44269504088896340736f;  // 1/sqrt(64) * log2(e)
  u16x4v qo, ko;
  qo.x = f2bf(oq0 * QSC); qo.y = f2bf(oq1 * QSC);
  qo.z = f2bf(oq2 * QSC); qo.w = f2bf(oq3 * QSC);
  ko.x = f2bf(ok0); ko.y = f2bf(ok1); ko.z = f2bf(ok2); ko.w = f2bf(ok3);
  size_t base = ((size_t)(b * NH + h) * SEQ + s) * HD + d0;
  *(u16x4v*)(Q + base) = qo;
  *(u16x4v*)(Kk + base) = ko;
}

// ---- V transpose: Vt[b][h][d][s] bf16 from qkv fp32 ----
__global__ __launch_bounds__(256) void post_v(const float* __restrict__ qkv,
                                              u16* __restrict__ Vt) {
  __shared__ u16 vt[64][65];
  int bid = blockIdx.x;
  int st = bid & 31, bh = bid >> 5;
  int b = bh >> 4, h = bh & 15;
  int t = threadIdx.x;
#pragma unroll
  for (int i = 0; i < 16; ++i) {
    int idx = i * 256 + t;
    int ss = idx >> 6, d = idx & 63;
    float v = qkv[(size_t)(b * SEQ + st * 64 + ss) * 3072 + 2048 + h * 64 + d];
    vt[ss][d] = f2bf(v);
  }
  __syncthreads();
#pragma unroll
  for (int i = 0; i < 16; ++i) {
    int idx = i * 256 + t;
    int dd = idx >> 6, ss = idx & 63;
    Vt[((size_t)bh * 64 + dd) * SEQ + st * 64 + ss] = vt[ss][dd];
  }
}

// ---- flash attention v3: LDS-staged K/V (2-phase double buffer,
//      global_load_lds + both-sides XOR swizzle), swapped-QK^T
//      in-register softmax, XCD-aware block swizzle ----
// Q[b][h][s][d], K same, Vt[b][h][d][s] -> O[b][s][h*64+d] (bf16)
__global__ __launch_bounds__(256) void attn_fwd(const u16* __restrict__ Q,
                                                const u16* __restrict__ K,
                                                const u16* __restrict__ Vt,
                                                u16* __restrict__ O) {
  __shared__ u16 Ks[2][64 * 64];
  __shared__ u16 Vs[2][64 * 64];
  __shared__ u16 P[4][16][80];

  // XCD-aware bijective swizzle: nwg=1024, 8 XCDs, 128 blocks/XCD
  // -> each XCD owns 4 complete heads (K/V stays in one L2).
  int bid0 = blockIdx.x;
  int bid = (bid0 & 7) * 128 + (bid0 >> 3);
  int qb = bid & 31, bh = bid >> 5;
  int b = bh >> 4, h = bh & 15;
  int t = threadIdx.x;
  int w = t >> 6, lane = t & 63;
  int l15 = lane & 15, l4 = lane >> 4;
  int q0 = qb * 64 + w * 16;
  const u16* Qh = Q + (size_t)bh * SEQ * HD;
  const u16* Kh = K + (size_t)bh * SEQ * HD;
  const u16* Vh = Vt + (size_t)bh * HD * SEQ;

  // staging geometry: tile = 64 rows x 64 u16 = 512 16B-chunks, 2 per thread.
  // linear LDS dest (chunk*16B); source col pre-swizzled so a swizzled
  // ds_read address reads the right data (rule #21 both-sides).
  int c0 = t, c1 = t + 256;
  int r0 = c0 >> 3, sc0 = ((c0 & 7) ^ (r0 & 7)) << 3;
  int r1 = c1 >> 3, sc1 = ((c1 & 7) ^ (r1 & 7)) << 3;
  const u16* Kg0 = Kh + (size_t)r0 * HD + sc0;
  const u16* Kg1 = Kh + (size_t)r1 * HD + sc1;
  const u16* Vg0 = Vh + (size_t)r0 * SEQ + sc0;
  const u16* Vg1 = Vh + (size_t)r1 * SEQ + sc1;

  // prologue: stage tile 0 into buf 0
  gload16(Kg0, &Ks[0][c0 * 8]);
  gload16(Kg1, &Ks[0][c1 * 8]);
  gload16(Vg0, &Vs[0][c0 * 8]);
  gload16(Vg1, &Vs[0][c1 * 8]);

  bf16x8 qf[2];
#pragma unroll
  for (int kf = 0; kf < 2; ++kf)
    qf[kf] = *(const bf16x8*)(Qh + (size_t)(q0 + l15) * HD + kf * 32 + l4 * 8);

  f32x4 oacc[4];
#pragma unroll
  for (int df = 0; df < 4; ++df) oacc[df] = (f32x4){0.f, 0.f, 0.f, 0.f};
  float mrun = -1e30f, lpart = 0.f;

  __syncthreads();  // drains vmcnt for the prologue stage

  int buf = 0;
  for (int it = 0; it < NT; ++it) {
    // issue next-tile stage first (loads fly under this tile's compute)
    if (it + 1 < NT) {
      size_t j0n = (size_t)(it + 1) * KVB;
      int nb = buf ^ 1;
      gload16(Kg0 + j0n * HD, &Ks[nb][c0 * 8]);
      gload16(Kg1 + j0n * HD, &Ks[nb][c1 * 8]);
      gload16(Vg0 + j0n, &Vs[nb][c0 * 8]);
      gload16(Vg1 + j0n, &Vs[nb][c1 * 8]);
    }
    const u16* Kb_ = Ks[buf];
    const u16* Vb_ = Vs[buf];
    // QK^T swapped: A=K rows, B=Q rows -> S^T (lane: q=l15, keys nf*16+l4*4+r)
    f32x4 sacc[4];
#pragma unroll
    for (int nf = 0; nf < 4; ++nf) sacc[nf] = (f32x4){0.f, 0.f, 0.f, 0.f};
#pragma unroll
    for (int nf = 0; nf < 4; ++nf) {
      int row = nf * 16 + l15;
      int swz = (row & 7) << 3;
#pragma unroll
      for (int kf = 0; kf < 2; ++kf) {
        bf16x8 kfr =
            *(const bf16x8*)(&Kb_[row * 64 + ((kf * 32 + l4 * 8) ^ swz)]);
        sacc[nf] =
            __builtin_amdgcn_mfma_f32_16x16x32_bf16(kfr, qf[kf], sacc[nf], 0, 0, 0);
      }
    }
    // V fragments from LDS (independent of softmax chain)
    bf16x8 vf[2][4];
#pragma unroll
    for (int df = 0; df < 4; ++df) {
      int row = df * 16 + l15;
      int swz = (row & 7) << 3;
#pragma unroll
      for (int kc = 0; kc < 2; ++kc)
        vf[kc][df] =
            *(const bf16x8*)(&Vb_[row * 64 + ((kc * 32 + l4 * 8) ^ swz)]);
    }
    // per-lane max over its 16 keys, then 2-shuffle cross-g reduce
    float m16 = sacc[0][0];
#pragma unroll
    for (int nf = 0; nf < 4; ++nf)
#pragma unroll
      for (int r = 0; r < 4; ++r) m16 = fmaxf(m16, sacc[nf][r]);
    m16 = fmaxf(m16, __shfl_xor(m16, 16, 64));
    m16 = fmaxf(m16, __shfl_xor(m16, 32, 64));
    // defer-max (T13)
    if (!__all(m16 - mrun <= 8.0f)) {
      float mnew = fmaxf(mrun, m16);
      float scl = exp2f(mrun - mnew);
      mrun = mnew;
      lpart *= scl;
      float sr[4];
#pragma unroll
      for (int r = 0; r < 4; ++r) sr[r] = __shfl(scl, l4 * 4 + r, 16);
#pragma unroll
      for (int df = 0; df < 4; ++df)
#pragma unroll
        for (int r = 0; r < 4; ++r) oacc[df][r] *= sr[r];
    }
    // p = exp2(s - m); per-lane partial rowsum (cross-lane reduce deferred)
    float rs = 0.f;
#pragma unroll
    for (int nf = 0; nf < 4; ++nf) {
      u16x4v pk;
#pragma unroll
      for (int r = 0; r < 4; ++r) {
        float pv = exp2f(sacc[nf][r] - mrun);
        rs += pv;
        pk[r] = f2bf(pv);
      }
      *(u16x4v*)(&P[w][l15][nf * 16 + l4 * 4]) = pk;
    }
    lpart += rs;
    asm volatile("s_waitcnt lgkmcnt(0)" ::: "memory");
    __builtin_amdgcn_sched_barrier(0);
#pragma unroll
    for (int kc = 0; kc < 2; ++kc) {
      bf16x8 pf = *(const bf16x8*)(&P[w][l15][kc * 32 + l4 * 8]);
#pragma unroll
      for (int df = 0; df < 4; ++df)
        oacc[df] =
            __builtin_amdgcn_mfma_f32_16x16x32_bf16(pf, vf[kc][df], oacc[df], 0, 0, 0);
    }
    __syncthreads();  // drains vmcnt (next tile staged) + protects buf swap
    buf ^= 1;
  }
  // deferred l reduction + epilogue
  lpart += __shfl_xor(lpart, 16, 64);
  lpart += __shfl_xor(lpart, 32, 64);
  float lr[4];
#pragma unroll
  for (int r = 0; r < 4; ++r) lr[r] = 1.0f / __shfl(lpart, l4 * 4 + r, 16);
#pragma unroll
  for (int df = 0; df < 4; ++df) {
    int dcol = h * 64 + df * 16 + l15;
#pragma unroll
    for (int r = 0; r < 4; ++r)
      O[(size_t)(b * SEQ + q0 + l4 * 4 + r) * DIM + dcol] = f2bf(oacc[df][r] * lr[r]);
  }
}

extern "C" void kernel_launch(void* const* d_in, const int* in_sizes, int n_in,
                              void* d_out, int out_size, void* d_ws,
                              size_t ws_size, hipStream_t stream) {
  const float* x = (const float*)d_in[0];
  const float* fsin = (const float*)d_in[1];
  const float* fcos = (const float*)d_in[2];
  const float* wq = (const float*)d_in[3];
  const float* wk = (const float*)d_in[4];
  const float* wv = (const float*)d_in[5];
  const float* wo = (const float*)d_in[6];
  const float* q_scale = (const float*)d_in[7];
  const float* q_bias = (const float*)d_in[8];
  const float* k_scale = (const float*)d_in[9];
  const float* k_bias = (const float*)d_in[10];
  float* out = (float*)d_out;

  u16* xb = (u16*)d_ws;                       // 4096*1024 bf16
  u16* wqkvT = xb + (size_t)ROWS * DIM;       // 3072*1024
  u16* woT = wqkvT + (size_t)3 * DIM * DIM;   // 1024*1024
  float* qkv = (float*)(woT + (size_t)DIM * DIM);  // 4096*3072 fp32
  u16* Qb = (u16*)(qkv + (size_t)ROWS * 3 * DIM);  // 32*2048*64
  u16* Kb = Qb + (size_t)BATCH * NH * SEQ * HD;
  u16* Vt = Kb + (size_t)BATCH * NH * SEQ * HD;
  u16* attnb = Vt + (size_t)BATCH * NH * SEQ * HD;  // 4096*1024

  convert_x<<<ROWS * DIM / 1024, 256, 0, stream>>>(x, xb);
  transpose_w<<<4 * 1024, 256, 0, stream>>>(wq, wk, wv, wo, wqkvT, woT);
  gemm_bt<<<(ROWS / 128) * (3 * DIM / 128), 256, 0, stream>>>(xb, wqkvT, qkv,
                                                              ROWS, 3 * DIM, DIM);
  post_qk<<<ROWS, 256, 0, stream>>>(qkv, fsin, fcos, q_scale, q_bias, k_scale,
                                    k_bias, Qb, Kb);
  post_v<<<BATCH * NH * (SEQ / 64), 256, 0, stream>>>(qkv, Vt);
  attn_fwd<<<BATCH * NH * (SEQ / 64), 256, 0, stream>>>(Qb, Kb, Vt, attnb);
  gemm_bt<<<(ROWS / 128) * (DIM / 128), 256, 0, stream>>>(attnb, woT, out, ROWS,
                                                          DIM, DIM);
}

// Round 7
// 267.085 us; speedup vs baseline: 1.5433x; 1.0292x over previous
//
#include <hip/hip_runtime.h>
#include <hip/hip_bf16.h>
#include <stddef.h>
#include <stdint.h>

#define DIM 1024
#define NH 16
#define HD 64
#define BATCH 2
#define SEQ 2048
#define ROWS (BATCH * SEQ) /* 4096 */
#define KVB 128
#define NT (SEQ / KVB) /* 16 */

typedef short bf16x8 __attribute__((ext_vector_type(8)));
typedef float f32x4 __attribute__((ext_vector_type(4)));
typedef unsigned short u16;
typedef unsigned short u16x4v __attribute__((ext_vector_type(4)));

#define AS1 __attribute__((address_space(1)))
#define AS3 __attribute__((address_space(3)))

__device__ __forceinline__ void gload16(const u16* g, u16* l) {
  __builtin_amdgcn_global_load_lds((const AS1 void*)g, (AS3 void*)l, 16, 0, 0);
}

__device__ __forceinline__ u16 f2bf(float f) {
  union { float f; unsigned u; } v; v.f = f;
  unsigned r = v.u + 0x7FFFu + ((v.u >> 16) & 1u);
  return (u16)(r >> 16);
}

// ---- merged: convert x (fp32->bf16) [bid<4096] + weight transpose [bid>=4096]
__global__ __launch_bounds__(256) void prep(
    const float* __restrict__ x, const float* __restrict__ wq,
    const float* __restrict__ wk, const float* __restrict__ wv,
    const float* __restrict__ wo, u16* __restrict__ xb,
    u16* __restrict__ wqkvT, u16* __restrict__ woT) {
  __shared__ float tile[32][33];
  int bid = blockIdx.x;
  int t = threadIdx.x;
  if (bid < 4096) {
    int i = (bid * 256 + t) * 4;
    float4 v = *(const float4*)(x + i);
    u16x4v o;
    o.x = f2bf(v.x); o.y = f2bf(v.y); o.z = f2bf(v.z); o.w = f2bf(v.w);
    *(u16x4v*)(xb + i) = o;
  } else {
    int bb = bid - 4096;
    int mat = bb >> 10;
    int tIdx = bb & 1023;
    int tr = tIdx >> 5, tc = tIdx & 31;
    const float* src = mat == 0 ? wq : mat == 1 ? wk : mat == 2 ? wv : wo;
#pragma unroll
    for (int i = 0; i < 4; ++i) {
      int idx = i * 256 + t;
      int r = idx >> 5, c = idx & 31;
      tile[r][c] = src[(tr * 32 + r) * DIM + tc * 32 + c];
    }
    __syncthreads();
    u16* dst = (mat < 3) ? (wqkvT + mat * DIM * DIM) : woT;
#pragma unroll
    for (int i = 0; i < 4; ++i) {
      int idx = i * 256 + t;
      int r = idx >> 5, c = idx & 31;
      dst[(tc * 32 + r) * DIM + tr * 32 + c] = f2bf(tile[c][r]);
    }
  }
}

// ------- bf16 GEMM, B^T input (m97 structure: 128x128 tile, BK=32,
//         global_load_lds width-16, linear LDS) -------
__global__ __launch_bounds__(256) void gemm_bt(
    const u16* __restrict__ A, const u16* __restrict__ BT,
    float* __restrict__ C, int M, int N, int K) {
  __shared__ u16 As[128 * 32];
  __shared__ u16 Bs[128 * 32];
  int ntn = N >> 7;
  int tm = blockIdx.x / ntn, tn = blockIdx.x % ntn;
  int m0 = tm << 7, n0 = tn << 7;
  int t = threadIdx.x;
  int w = t >> 6, lane = t & 63;
  int l15 = lane & 15, l4 = lane >> 4;
  int wr = w >> 1, wc = w & 1;

  f32x4 acc[4][4];
#pragma unroll
  for (int i = 0; i < 4; ++i)
#pragma unroll
    for (int j = 0; j < 4; ++j) acc[i][j] = (f32x4){0.f, 0.f, 0.f, 0.f};

  int srow = t >> 2, scol = (t & 3) << 3;
  const u16* Ag = A + (size_t)(m0 + srow) * K + scol;
  const u16* Bg = BT + (size_t)(n0 + srow) * K + scol;
  u16* Asl = &As[t * 8];
  u16* Bsl = &Bs[t * 8];
  size_t half = (size_t)64 * K;

  for (int kt = 0; kt < K; kt += 32) {
    __syncthreads();
    gload16(Ag + kt, Asl);
    gload16(Ag + half + kt, Asl + 2048);
    gload16(Bg + kt, Bsl);
    gload16(Bg + half + kt, Bsl + 2048);
    __syncthreads();
    bf16x8 af[4], bfr[4];
#pragma unroll
    for (int i = 0; i < 4; ++i)
      af[i] = *(const bf16x8*)(&As[(wr * 64 + i * 16 + l15) * 32 + l4 * 8]);
#pragma unroll
    for (int j = 0; j < 4; ++j)
      bfr[j] = *(const bf16x8*)(&Bs[(wc * 64 + j * 16 + l15) * 32 + l4 * 8]);
#pragma unroll
    for (int i = 0; i < 4; ++i)
#pragma unroll
      for (int j = 0; j < 4; ++j)
        acc[i][j] = __builtin_amdgcn_mfma_f32_16x16x32_bf16(af[i], bfr[j],
                                                            acc[i][j], 0, 0, 0);
  }
#pragma unroll
  for (int i = 0; i < 4; ++i)
#pragma unroll
    for (int j = 0; j < 4; ++j) {
      int m = m0 + wr * 64 + i * 16 + l4 * 4;
      int n = n0 + wc * 64 + j * 16 + l15;
#pragma unroll
      for (int r = 0; r < 4; ++r) C[(size_t)(m + r) * N + n] = acc[i][j][r];
    }
}

// ---- LN + rotary for Q,K rows; emits bf16 Q,K in [b][h][s][d] ----
__global__ __launch_bounds__(256) void post_qk(
    const float* __restrict__ qkv, const float* __restrict__ fsin,
    const float* __restrict__ fcos, const float* __restrict__ qsc,
    const float* __restrict__ qbi, const float* __restrict__ ksc,
    const float* __restrict__ kbi, u16* __restrict__ Q, u16* __restrict__ Kk) {
  int row = blockIdx.x;  // b*SEQ + s
  int b = row >> 11, s = row & 2047;
  int t = threadIdx.x;
  const float* qrow = qkv + (size_t)row * 3072;
  const float* krow = qrow + DIM;
  float4 qv = *(const float4*)(qrow + t * 4);
  float4 kv = *(const float4*)(krow + t * 4);
  float qsum = qv.x + qv.y + qv.z + qv.w;
  float qss = qv.x * qv.x + qv.y * qv.y + qv.z * qv.z + qv.w * qv.w;
  float ksum = kv.x + kv.y + kv.z + kv.w;
  float kss = kv.x * kv.x + kv.y * kv.y + kv.z * kv.z + kv.w * kv.w;
#pragma unroll
  for (int off = 1; off < 64; off <<= 1) {
    qsum += __shfl_xor(qsum, off, 64);
    qss += __shfl_xor(qss, off, 64);
    ksum += __shfl_xor(ksum, off, 64);
    kss += __shfl_xor(kss, off, 64);
  }
  __shared__ float red[4][4];
  int w = t >> 6;
  if ((t & 63) == 0) {
    red[w][0] = qsum; red[w][1] = qss; red[w][2] = ksum; red[w][3] = kss;
  }
  __syncthreads();
  qsum = red[0][0] + red[1][0] + red[2][0] + red[3][0];
  qss = red[0][1] + red[1][1] + red[2][1] + red[3][1];
  ksum = red[0][2] + red[1][2] + red[2][2] + red[3][2];
  kss = red[0][3] + red[1][3] + red[2][3] + red[3][3];
  const float inv = 1.0f / 1024.0f;
  float muq = qsum * inv;
  float rq = rsqrtf(qss * inv - muq * muq + 1e-6f);
  float muk = ksum * inv;
  float rk = rsqrtf(kss * inv - muk * muk + 1e-6f);

  int e0 = t * 4;
  int h = e0 >> 6, d0 = e0 & 63;
  float q0 = (qv.x - muq) * rq * qsc[e0 + 0] + qbi[e0 + 0];
  float q1 = (qv.y - muq) * rq * qsc[e0 + 1] + qbi[e0 + 1];
  float q2 = (qv.z - muq) * rq * qsc[e0 + 2] + qbi[e0 + 2];
  float q3 = (qv.w - muq) * rq * qsc[e0 + 3] + qbi[e0 + 3];
  float k0 = (kv.x - muk) * rk * ksc[e0 + 0] + kbi[e0 + 0];
  float k1 = (kv.y - muk) * rk * ksc[e0 + 1] + kbi[e0 + 1];
  float k2 = (kv.z - muk) * rk * ksc[e0 + 2] + kbi[e0 + 2];
  float k3 = (kv.w - muk) * rk * ksc[e0 + 3] + kbi[e0 + 3];

  int p0 = d0 >> 1;
  float c0 = fcos[s * 32 + p0], s0 = fsin[s * 32 + p0];
  float c1 = fcos[s * 32 + p0 + 1], s1 = fsin[s * 32 + p0 + 1];
  float oq0 = q0 * c0 - q1 * s0, oq1 = q0 * s0 + q1 * c0;
  float oq2 = q2 * c1 - q3 * s1, oq3 = q2 * s1 + q3 * c1;
  float ok0 = k0 * c0 - k1 * s0, ok1 = k0 * s0 + k1 * c0;
  float ok2 = k2 * c1 - k3 * s1, ok3 = k2 * s1 + k3 * c1;

  const float QSC = 0.125f * 1.44269504088896340736f;  // 1/sqrt(64) * log2(e)
  u16x4v qo, ko;
  qo.x = f2bf(oq0 * QSC); qo.y = f2bf(oq1 * QSC);
  qo.z = f2bf(oq2 * QSC); qo.w = f2bf(oq3 * QSC);
  ko.x = f2bf(ok0); ko.y = f2bf(ok1); ko.z = f2bf(ok2); ko.w = f2bf(ok3);
  size_t base = ((size_t)(b * NH + h) * SEQ + s) * HD + d0;
  *(u16x4v*)(Q + base) = qo;
  *(u16x4v*)(Kk + base) = ko;
}

// ---- V transpose: Vt[b][h][d][s] bf16 from qkv fp32 ----
__global__ __launch_bounds__(256) void post_v(const float* __restrict__ qkv,
                                              u16* __restrict__ Vt) {
  __shared__ u16 vt[64][65];
  int bid = blockIdx.x;
  int st = bid & 31, bh = bid >> 5;
  int b = bh >> 4, h = bh & 15;
  int t = threadIdx.x;
#pragma unroll
  for (int i = 0; i < 16; ++i) {
    int idx = i * 256 + t;
    int ss = idx >> 6, d = idx & 63;
    float v = qkv[(size_t)(b * SEQ + st * 64 + ss) * 3072 + 2048 + h * 64 + d];
    vt[ss][d] = f2bf(v);
  }
  __syncthreads();
#pragma unroll
  for (int i = 0; i < 16; ++i) {
    int idx = i * 256 + t;
    int dd = idx >> 6, ss = idx & 63;
    Vt[((size_t)bh * 64 + dd) * SEQ + st * 64 + ss] = vt[ss][dd];
  }
}

// ---- flash attention v5: PROVEN round-3 sync skeleton (2-buffer,
//      __syncthreads full drain), KVB=128 (half-P processing), setprio,
//      swapped-QK^T in-register softmax, XCD swizzle ----
__global__ __launch_bounds__(256) void attn_fwd(const u16* __restrict__ Q,
                                                const u16* __restrict__ K,
                                                const u16* __restrict__ Vt,
                                                u16* __restrict__ O) {
  __shared__ u16 Ks[2][KVB * HD];  // [128 rows][64 cols]
  __shared__ u16 Vs[2][HD * KVB];  // [64 rows][128 cols]
  __shared__ u16 P[4][16][80];

  // XCD-aware bijective swizzle: nwg=1024 -> each XCD owns 4 complete heads.
  int bid0 = blockIdx.x;
  int bid = (bid0 & 7) * 128 + (bid0 >> 3);
  int qb = bid & 31, bh = bid >> 5;
  int b = bh >> 4, h = bh & 15;
  int t = threadIdx.x;
  int w = t >> 6, lane = t & 63;
  int l15 = lane & 15, l4 = lane >> 4;
  int q0 = qb * 64 + w * 16;
  const u16* Qh = Q + (size_t)bh * SEQ * HD;
  const u16* Kh = K + (size_t)bh * SEQ * HD;
  const u16* Vh = Vt + (size_t)bh * HD * SEQ;

  // staging: K tile 128x64 u16 = 1024 chunks(16B); V tile 64x128 = 1024.
  // 4 chunks each per thread. Linear LDS dest; source col pre-swizzled
  // (rule #21 both-sides XOR; V chunk idx 0..15, XOR affects low 3 bits).
  const u16* Kg[4];
  const u16* Vg[4];
#pragma unroll
  for (int i = 0; i < 4; ++i) {
    int c = t + 256 * i;
    int kr = c >> 3, kcol = ((c & 7) ^ (kr & 7)) << 3;
    Kg[i] = Kh + (size_t)kr * HD + kcol;
    int vr = c >> 4, vcol = ((c & 15) ^ (vr & 7)) << 3;
    Vg[i] = Vh + (size_t)vr * SEQ + vcol;
  }

#define STAGE(tile, bufi)                                  \
  do {                                                     \
    size_t j0s = (size_t)(tile) * KVB;                     \
    gload16(Kg[0] + j0s * HD, &Ks[(bufi)][(t)*8]);         \
    gload16(Kg[1] + j0s * HD, &Ks[(bufi)][(t + 256) * 8]); \
    gload16(Kg[2] + j0s * HD, &Ks[(bufi)][(t + 512) * 8]); \
    gload16(Kg[3] + j0s * HD, &Ks[(bufi)][(t + 768) * 8]); \
    gload16(Vg[0] + j0s, &Vs[(bufi)][(t)*8]);              \
    gload16(Vg[1] + j0s, &Vs[(bufi)][(t + 256) * 8]);      \
    gload16(Vg[2] + j0s, &Vs[(bufi)][(t + 512) * 8]);      \
    gload16(Vg[3] + j0s, &Vs[(bufi)][(t + 768) * 8]);      \
  } while (0)

  // prologue: stage tile 0 into buf 0
  STAGE(0, 0);

  bf16x8 qf[2];
#pragma unroll
  for (int kf = 0; kf < 2; ++kf)
    qf[kf] = *(const bf16x8*)(Qh + (size_t)(q0 + l15) * HD + kf * 32 + l4 * 8);

  f32x4 oacc[4];
#pragma unroll
  for (int df = 0; df < 4; ++df) oacc[df] = (f32x4){0.f, 0.f, 0.f, 0.f};
  float mrun = -1e30f, lpart = 0.f;

  __syncthreads();  // full drain: tile 0 resident

  int buf = 0;
  for (int it = 0; it < NT; ++it) {
    if (it + 1 < NT) STAGE(it + 1, buf ^ 1);  // flies under this tile's compute
    const u16* Kb_ = &Ks[buf][0];
    const u16* Vb_ = &Vs[buf][0];

    // QK^T swapped: lane (q=l15) holds keys nf*16 + l4*4 + r, nf=0..7
    f32x4 sacc[8];
#pragma unroll
    for (int nf = 0; nf < 8; ++nf) sacc[nf] = (f32x4){0.f, 0.f, 0.f, 0.f};
    __builtin_amdgcn_s_setprio(1);
#pragma unroll
    for (int nf = 0; nf < 8; ++nf) {
      int row = nf * 16 + l15;
      int swz = (row & 7) << 3;
#pragma unroll
      for (int kf = 0; kf < 2; ++kf) {
        bf16x8 kfr =
            *(const bf16x8*)(&Kb_[row * 64 + ((kf * 32 + l4 * 8) ^ swz)]);
        sacc[nf] =
            __builtin_amdgcn_mfma_f32_16x16x32_bf16(kfr, qf[kf], sacc[nf], 0, 0, 0);
      }
    }
    __builtin_amdgcn_s_setprio(0);

    // V fragments (independent of softmax chain)
    bf16x8 vf[4][4];
#pragma unroll
    for (int df = 0; df < 4; ++df) {
      int row = df * 16 + l15;
      int swz = (row & 7) << 3;
#pragma unroll
      for (int kc = 0; kc < 4; ++kc)
        vf[kc][df] =
            *(const bf16x8*)(&Vb_[row * 128 + ((kc * 32 + l4 * 8) ^ swz)]);
    }

    // per-lane max over its 32 keys, 2-shuffle cross-group reduce
    float m16 = sacc[0][0];
#pragma unroll
    for (int nf = 0; nf < 8; ++nf)
#pragma unroll
      for (int r = 0; r < 4; ++r) m16 = fmaxf(m16, sacc[nf][r]);
    m16 = fmaxf(m16, __shfl_xor(m16, 16, 64));
    m16 = fmaxf(m16, __shfl_xor(m16, 32, 64));
    // defer-max (T13)
    if (!__all(m16 - mrun <= 8.0f)) {
      float mnew = fmaxf(mrun, m16);
      float scl = exp2f(mrun - mnew);
      mrun = mnew;
      lpart *= scl;
      float sr[4];
#pragma unroll
      for (int r = 0; r < 4; ++r) sr[r] = __shfl(scl, l4 * 4 + r, 16);
#pragma unroll
      for (int df = 0; df < 4; ++df)
#pragma unroll
        for (int r = 0; r < 4; ++r) oacc[df][r] *= sr[r];
    }

    float rs = 0.f;
    // ---- half 0: keys [0,64) -> P, PV with V cols [0,64) ----
#pragma unroll
    for (int j = 0; j < 4; ++j) {
      float p0 = exp2f(sacc[j][0] - mrun);
      float p1 = exp2f(sacc[j][1] - mrun);
      float p2 = exp2f(sacc[j][2] - mrun);
      float p3 = exp2f(sacc[j][3] - mrun);
      rs += (p0 + p1) + (p2 + p3);
      __hip_bfloat162 pa, pb;
      pa.x = __float2bfloat16(p0); pa.y = __float2bfloat16(p1);
      pb.x = __float2bfloat16(p2); pb.y = __float2bfloat16(p3);
      uint2 pk2;
      pk2.x = *reinterpret_cast<unsigned int*>(&pa);
      pk2.y = *reinterpret_cast<unsigned int*>(&pb);
      *(uint2*)(&P[w][l15][j * 16 + l4 * 4]) = pk2;
    }
    asm volatile("s_waitcnt lgkmcnt(0)" ::: "memory");
    __builtin_amdgcn_sched_barrier(0);
    __builtin_amdgcn_s_setprio(1);
#pragma unroll
    for (int kc = 0; kc < 2; ++kc) {
      bf16x8 pf = *(const bf16x8*)(&P[w][l15][kc * 32 + l4 * 8]);
#pragma unroll
      for (int df = 0; df < 4; ++df)
        oacc[df] =
            __builtin_amdgcn_mfma_f32_16x16x32_bf16(pf, vf[kc][df], oacc[df], 0, 0, 0);
    }
    __builtin_amdgcn_s_setprio(0);
    // ---- half 1: keys [64,128) -> P (in-wave DS order makes the
    //      overwrite safe), PV with V cols [64,128) ----
#pragma unroll
    for (int j = 0; j < 4; ++j) {
      float p0 = exp2f(sacc[4 + j][0] - mrun);
      float p1 = exp2f(sacc[4 + j][1] - mrun);
      float p2 = exp2f(sacc[4 + j][2] - mrun);
      float p3 = exp2f(sacc[4 + j][3] - mrun);
      rs += (p0 + p1) + (p2 + p3);
      __hip_bfloat162 pa, pb;
      pa.x = __float2bfloat16(p0); pa.y = __float2bfloat16(p1);
      pb.x = __float2bfloat16(p2); pb.y = __float2bfloat16(p3);
      uint2 pk2;
      pk2.x = *reinterpret_cast<unsigned int*>(&pa);
      pk2.y = *reinterpret_cast<unsigned int*>(&pb);
      *(uint2*)(&P[w][l15][j * 16 + l4 * 4]) = pk2;
    }
    asm volatile("s_waitcnt lgkmcnt(0)" ::: "memory");
    __builtin_amdgcn_sched_barrier(0);
    __builtin_amdgcn_s_setprio(1);
#pragma unroll
    for (int kc = 0; kc < 2; ++kc) {
      bf16x8 pf = *(const bf16x8*)(&P[w][l15][kc * 32 + l4 * 8]);
#pragma unroll
      for (int df = 0; df < 4; ++df)
        oacc[df] = __builtin_amdgcn_mfma_f32_16x16x32_bf16(pf, vf[kc + 2][df],
                                                           oacc[df], 0, 0, 0);
    }
    __builtin_amdgcn_s_setprio(0);

    lpart += rs;
    __syncthreads();  // full drain: next tile resident, all LDS ops done
    buf ^= 1;
  }
#undef STAGE
  // deferred l reduction + epilogue
  lpart += __shfl_xor(lpart, 16, 64);
  lpart += __shfl_xor(lpart, 32, 64);
  float lr[4];
#pragma unroll
  for (int r = 0; r < 4; ++r) lr[r] = 1.0f / __shfl(lpart, l4 * 4 + r, 16);
#pragma unroll
  for (int df = 0; df < 4; ++df) {
    int dcol = h * 64 + df * 16 + l15;
#pragma unroll
    for (int r = 0; r < 4; ++r)
      O[(size_t)(b * SEQ + q0 + l4 * 4 + r) * DIM + dcol] = f2bf(oacc[df][r] * lr[r]);
  }
}

extern "C" void kernel_launch(void* const* d_in, const int* in_sizes, int n_in,
                              void* d_out, int out_size, void* d_ws,
                              size_t ws_size, hipStream_t stream) {
  const float* x = (const float*)d_in[0];
  const float* fsin = (const float*)d_in[1];
  const float* fcos = (const float*)d_in[2];
  const float* wq = (const float*)d_in[3];
  const float* wk = (const float*)d_in[4];
  const float* wv = (const float*)d_in[5];
  const float* wo = (const float*)d_in[6];
  const float* q_scale = (const float*)d_in[7];
  const float* q_bias = (const float*)d_in[8];
  const float* k_scale = (const float*)d_in[9];
  const float* k_bias = (const float*)d_in[10];
  float* out = (float*)d_out;

  u16* xb = (u16*)d_ws;                       // 4096*1024 bf16
  u16* wqkvT = xb + (size_t)ROWS * DIM;       // 3072*1024
  u16* woT = wqkvT + (size_t)3 * DIM * DIM;   // 1024*1024
  float* qkv = (float*)(woT + (size_t)DIM * DIM);  // 4096*3072 fp32
  u16* Qb = (u16*)(qkv + (size_t)ROWS * 3 * DIM);  // 32*2048*64
  u16* Kb = Qb + (size_t)BATCH * NH * SEQ * HD;
  u16* Vt = Kb + (size_t)BATCH * NH * SEQ * HD;
  u16* attnb = Vt + (size_t)BATCH * NH * SEQ * HD;  // 4096*1024

  prep<<<8192, 256, 0, stream>>>(x, wq, wk, wv, wo, xb, wqkvT, woT);
  gemm_bt<<<(ROWS / 128) * (3 * DIM / 128), 256, 0, stream>>>(xb, wqkvT, qkv,
                                                              ROWS, 3 * DIM, DIM);
  post_qk<<<ROWS, 256, 0, stream>>>(qkv, fsin, fcos, q_scale, q_bias, k_scale,
                                    k_bias, Qb, Kb);
  post_v<<<BATCH * NH * (SEQ / 64), 256, 0, stream>>>(qkv, Vt);
  attn_fwd<<<BATCH * NH * (SEQ / 64), 256, 0, stream>>>(Qb, Kb, Vt, attnb);
  gemm_bt<<<(ROWS / 128) * (DIM / 128), 256, 0, stream>>>(attnb, woT, out, ROWS,
                                                          DIM, DIM);
}